// Round 1
// 1017.562 us; speedup vs baseline: 1.1722x; 1.1722x over previous
//
#include <hip/hip_runtime.h>

// Problem constants (B,T,E,H fixed by the reference)
#define B_   256
#define T_   200
#define E_   512
#define H_   8
#define Dh_  64
#define F_   2048            // 4*E
#define M_   (B_ * T_)       // 51200 rows
#define MH_  (M_ / 2)        // 25600 rows per FFN chunk
#define SCALE 22.62741699796952f   // sqrt(512) in fp32
#define NEGV  -4294967296.0f       // fp32(-(2^32)+1)

typedef __attribute__((ext_vector_type(8))) short bf16x8;
typedef __attribute__((ext_vector_type(4))) float f32x4;

__device__ __forceinline__ float bf2f(unsigned short u) {
    union { unsigned u32; float f; } v; v.u32 = ((unsigned)u) << 16; return v.f;
}
__device__ __forceinline__ unsigned short f2bf(float f) {
    union { float f32; unsigned u; } v; v.f32 = f;
    unsigned r = v.u + 0x7FFFu + ((v.u >> 16) & 1u);   // RNE
    return (unsigned short)(r >> 16);
}
__device__ __forceinline__ unsigned pack_hilo(float f) {
    unsigned short hi = f2bf(f);
    unsigned short lo = f2bf(f - bf2f(hi));
    return (unsigned)hi | ((unsigned)lo << 16);
}
__device__ __forceinline__ void load_lds16(const unsigned short* g, unsigned short* l) {
    __builtin_amdgcn_global_load_lds(
        (const __attribute__((address_space(1))) unsigned int*)g,
        (__attribute__((address_space(3))) unsigned int*)l, 16, 0, 0);
}

// ---------------------------------------------------------------------------
// Kernel 0: pos-encoding add + hi/lo bf16 split, IN-PLACE over queries/keys.
// ---------------------------------------------------------------------------
__global__ __launch_bounds__(256) void k_prep(
    float* __restrict__ q, float* __restrict__ k,
    const float* __restrict__ pos_q, const float* __restrict__ pos_k)
{
    const int z = blockIdx.y;
    float* X = z ? k : q;
    const float* Ps = z ? pos_k : pos_q;
    size_t idx = ((size_t)blockIdx.x * 256 + threadIdx.x) * 4;
    int row = (int)(idx >> 9);
    int col = (int)(idx & 511);
    int t = row % T_;
    float4 v = *(const float4*)&X[idx];
    float4 p = *(const float4*)&Ps[(size_t)t * E_ + col];
    uint4 o;
    o.x = pack_hilo(v.x + p.x * SCALE);
    o.y = pack_hilo(v.y + p.y * SCALE);
    o.z = pack_hilo(v.z + p.z * SCALE);
    o.w = pack_hilo(v.w + p.w * SCALE);
    *(uint4*)&X[idx] = o;
}

// ---------------------------------------------------------------------------
// Kernel 1: weight transpose + hi/lo split: W fp32 [K][N] -> Wh,Wl bf16 [N][K]
// ---------------------------------------------------------------------------
__global__ __launch_bounds__(256) void k_trw(
    const float* __restrict__ in, unsigned short* __restrict__ oh,
    unsigned short* __restrict__ ol)
{
    const int k0 = blockIdx.x * 64, n0 = blockIdx.y * 64;
    const int tid = threadIdx.x;
    __shared__ unsigned short th[64][65], tl[64][65];
#pragma unroll
    for (int i = 0; i < 16; i++) {
        int e = i * 256 + tid;
        int r = e >> 6, c = e & 63;
        float f = in[(size_t)(k0 + r) * 512 + n0 + c];
        unsigned short h = f2bf(f);
        th[r][c] = h;
        tl[r][c] = f2bf(f - bf2f(h));
    }
    __syncthreads();
#pragma unroll
    for (int i = 0; i < 16; i++) {
        int e = i * 256 + tid;
        int r = e >> 6, c = e & 63;
        oh[(size_t)(n0 + r) * 512 + k0 + c] = th[c][r];
        ol[(size_t)(n0 + r) * 512 + k0 + c] = tl[c][r];
    }
}

// ---------------------------------------------------------------------------
// Kernel 2: split-precision projection GEMM via MFMA (proven round 5).
// ---------------------------------------------------------------------------
template<int NPROD, bool SPLIT>
__global__ __launch_bounds__(256) void k_projx(
    const unsigned int* __restrict__ Apk,
    const unsigned short* __restrict__ Bh,
    const unsigned short* __restrict__ Bl,
    unsigned short* __restrict__ Chi,
    unsigned short* __restrict__ Clo)
{
    const int K = 512, N = 512;
    __shared__ alignas(16) unsigned short AsH[128 * 32];
    __shared__ alignas(16) unsigned short AsL[128 * 32];
    __shared__ alignas(16) unsigned short BsH[128 * 32];
    __shared__ alignas(16) unsigned short BsL[(NPROD >= 3) ? 128 * 32 : 8];

    const int tid = threadIdx.x;
    const int w = tid >> 6, lane = tid & 63;
    const int m0 = blockIdx.x * 128, n0 = blockIdx.y * 128;
    const int mr = lane & 15, q = lane >> 4;

    f32x4 acc[4][4];
#pragma unroll
    for (int i = 0; i < 4; i++)
#pragma unroll
        for (int j = 0; j < 4; j++) acc[i][j] = (f32x4){0.f, 0.f, 0.f, 0.f};

    const int c0  = w * 64 + lane;
    const int c1  = 256 + w * 64 + lane;
    const int bm0 = c0 >> 2, bq0 = (c0 & 3) ^ ((bm0 >> 1) & 3);
    const int bm1 = c1 >> 2, bq1 = (c1 & 3) ^ ((bm1 >> 1) & 3);
    const unsigned short* gB0h = Bh + (size_t)(n0 + bm0) * K + bq0 * 8;
    const unsigned short* gB1h = Bh + (size_t)(n0 + bm1) * K + bq1 * 8;
    const unsigned short* gB0l = (NPROD >= 3) ? Bl + (size_t)(n0 + bm0) * K + bq0 * 8 : nullptr;
    const unsigned short* gB1l = (NPROD >= 3) ? Bl + (size_t)(n0 + bm1) * K + bq1 * 8 : nullptr;
    unsigned short* lB0h = BsH + (size_t)(w * 64) * 8;
    unsigned short* lB1h = BsH + (size_t)(256 + w * 64) * 8;
    unsigned short* lB0l = BsL + (size_t)(w * 64) * 8;
    unsigned short* lB1l = BsL + (size_t)(256 + w * 64) * 8;

    int caf[4], cbf[4];
#pragma unroll
    for (int t4 = 0; t4 < 4; t4++) {
        int ma = (w & 1) * 64 + t4 * 16 + mr;
        caf[t4] = ma * 4 + (q ^ ((ma >> 1) & 3));
        int nb = (w >> 1) * 64 + t4 * 16 + mr;
        cbf[t4] = nb * 4 + (q ^ ((nb >> 1) & 3));
    }

    for (int k0 = 0; k0 < K; k0 += 32) {
#pragma unroll
        for (int i = 0; i < 4; i++) {
            int cc = i * 256 + tid;
            int am = cc >> 3, aq = cc & 7;
            uint4 v = *(const uint4*)&Apk[(size_t)(m0 + am) * K + k0 + aq * 4];
            ushort4 h, l;
            h.x = (unsigned short)(v.x & 0xffff); l.x = (unsigned short)(v.x >> 16);
            h.y = (unsigned short)(v.y & 0xffff); l.y = (unsigned short)(v.y >> 16);
            h.z = (unsigned short)(v.z & 0xffff); l.z = (unsigned short)(v.z >> 16);
            h.w = (unsigned short)(v.w & 0xffff); l.w = (unsigned short)(v.w >> 16);
            int cp  = am * 4 + ((aq >> 1) ^ ((am >> 1) & 3));
            int off = cp * 8 + (aq & 1) * 4;
            *(ushort4*)&AsH[off] = h;
            *(ushort4*)&AsL[off] = l;
        }
        load_lds16(gB0h + k0, lB0h);
        load_lds16(gB1h + k0, lB1h);
        if (NPROD >= 3) {
            load_lds16(gB0l + k0, lB0l);
            load_lds16(gB1l + k0, lB1l);
        }
        __syncthreads();

        bf16x8 afh[4], afl[4], bgh[4], bgl[4];
#pragma unroll
        for (int t4 = 0; t4 < 4; t4++) {
            afh[t4] = *(const bf16x8*)&AsH[caf[t4] * 8];
            if (NPROD >= 2) afl[t4] = *(const bf16x8*)&AsL[caf[t4] * 8];
            bgh[t4] = *(const bf16x8*)&BsH[cbf[t4] * 8];
            if (NPROD >= 3) bgl[t4] = *(const bf16x8*)&BsL[cbf[t4] * 8];
        }
#pragma unroll
        for (int i = 0; i < 4; i++)
#pragma unroll
            for (int j = 0; j < 4; j++) {
                acc[i][j] = __builtin_amdgcn_mfma_f32_16x16x32_bf16(
                    afh[i], bgh[j], acc[i][j], 0, 0, 0);
                if (NPROD >= 3)
                    acc[i][j] = __builtin_amdgcn_mfma_f32_16x16x32_bf16(
                        afh[i], bgl[j], acc[i][j], 0, 0, 0);
                if (NPROD >= 2)
                    acc[i][j] = __builtin_amdgcn_mfma_f32_16x16x32_bf16(
                        afl[i], bgh[j], acc[i][j], 0, 0, 0);
            }
        __syncthreads();
    }

#pragma unroll
    for (int i = 0; i < 4; i++) {
        int row = m0 + (w & 1) * 64 + i * 16 + q * 4;
#pragma unroll
        for (int j = 0; j < 4; j++) {
            int col = n0 + (w >> 1) * 64 + j * 16 + mr;
#pragma unroll
            for (int r = 0; r < 4; r++) {
                float v = acc[i][j][r];
                unsigned short hi = f2bf(v);
                Chi[(size_t)(row + r) * N + col] = hi;
                if (SPLIT)
                    Clo[(size_t)(row + r) * N + col] = f2bf(v - bf2f(hi));
            }
        }
    }
}

// ---------------------------------------------------------------------------
// Kernel 3: FLASH attention per (b,h) — v2 (this round).
//   * 512 threads (8 waves), __launch_bounds__(512,4): LDS 73728 B -> 2
//     blocks/CU -> 16 waves/CU (was 8).  Each wave owns q-tiles {w, w+8}.
//   * K-hi/K-lo/V^T staged PER 64-col CHUNK, double-buffered: ONE barrier
//     per chunk (stage of chunk c+1 issues before compute of chunk c).
//   * Exact mask-aware skipping: chunks with c*64>=kl contribute exactly 0
//     (exp(NEG-m)==0 whenever any real col exists) -> cmax=ceil(kl/64),
//     guarded for the kl==1 degenerate all-masked-row (needs all chunks for
//     uniform weights).  q-tiles with qt*16>=ql are zeroed by the epilogue
//     inv=0 path -> skip their compute entirely (epilogue writes residual).
//   * Q-hi fragments hoisted to registers across the chunk loop (Q-lo
//     deliberately NOT hoisted: stays under the 128-VGPR/4-wave cap).
//   * s_setprio(1) around MFMA clusters (T5).
//   Numerics identical to the proven round-5 kernel: 6-MFMA split-precision
//   QK^T, online softmax, masks col>=kl / col==row -> NEGV, pad -> -INF.
// ---------------------------------------------------------------------------
__global__ __launch_bounds__(512, 4) void k_attn_flash(
    const unsigned short* __restrict__ Qhi, const unsigned short* __restrict__ Qlo,
    const unsigned short* __restrict__ Khi, const unsigned short* __restrict__ Klo,
    const int* __restrict__ qlen, const int* __restrict__ klen,
    const unsigned int* __restrict__ Apk,   // packed q_in hi/lo (residual)
    unsigned short* VX)   // V (read) and out1 (write) — same buffer
{
    const int bh = blockIdx.x;
    const int b = bh >> 3, h = bh & 7;
    const int tid = threadIdx.x;
    const int w = tid >> 6, l = tid & 63;
    const int mr = l & 15, q4 = l >> 4;

    __shared__ alignas(16) unsigned short Kh_s[2][64 * 72];   //  9216 B x2
    __shared__ alignas(16) unsigned short Kl_s[2][64 * 72];   //  9216 B x2
    __shared__ alignas(16) unsigned short Vt_s[2][64 * 72];   //  9216 B x2 (V^T chunk)
    __shared__ alignas(16) unsigned short P_s[8][16 * 72];    // 18432 B (per wave)

    const int kl = klen[b], ql = qlen[b];
    // chunks with c*64>=kl are exactly zero-weight unless the whole row is
    // masked — only possible when kl==1 (row 0, diag+len cover everything).
    const int cmax = (kl > 1) ? ((kl + 63) >> 6) : 4;

    // stage chunk cs (cols cs*64..+63) into buffer sb: K row-major [64][72],
    // V transposed [d][64].  K rows for n>=T_ left stale (masked to -INF
    // before exp); V pad cols zeroed (P==0 there, avoid 0*garbage concerns).
    auto stage = [&](int cs, int sb) {
#pragma unroll
        for (int ii = 0; ii < 2; ii++) {
            const int idx = ii * 512 + tid;
            const int jn = idx >> 4, dq = idx & 15;
            const int n = cs * 64 + jn;
            if (n < T_) {
                const size_t g = (size_t)(b * T_ + n) * E_ + h * 64 + dq * 4;
                *(uint2*)&Kh_s[sb][jn * 72 + dq * 4] = *(const uint2*)&Khi[g];
                *(uint2*)&Kl_s[sb][jn * 72 + dq * 4] = *(const uint2*)&Klo[g];
                ushort4 v = *(const ushort4*)&VX[g];
                Vt_s[sb][(dq * 4 + 0) * 72 + jn] = v.x;
                Vt_s[sb][(dq * 4 + 1) * 72 + jn] = v.y;
                Vt_s[sb][(dq * 4 + 2) * 72 + jn] = v.z;
                Vt_s[sb][(dq * 4 + 3) * 72 + jn] = v.w;
            } else {
                Vt_s[sb][(dq * 4 + 0) * 72 + jn] = 0;
                Vt_s[sb][(dq * 4 + 1) * 72 + jn] = 0;
                Vt_s[sb][(dq * 4 + 2) * 72 + jn] = 0;
                Vt_s[sb][(dq * 4 + 3) * 72 + jn] = 0;
            }
        }
    };

    // hoist Q-hi fragments across the chunk loop (16 VGPRs)
    bf16x8 qh0[2], qh1[2];
#pragma unroll
    for (int j = 0; j < 2; j++) {
        const int qt = w + 8 * j;
        if (qt < 13 && qt * 16 < ql) {
            const size_t qoff = (size_t)(b * T_ + qt * 16 + mr) * E_ + h * 64 + q4 * 8;
            qh0[j] = *(const bf16x8*)&Qhi[qoff];
            qh1[j] = *(const bf16x8*)&Qhi[qoff + 32];
        }
    }

    f32x4 O[2][4];           // [j][nt]
    float m_r[2][4], l_r[2][4];
#pragma unroll
    for (int j = 0; j < 2; j++) {
#pragma unroll
        for (int nt = 0; nt < 4; nt++) O[j][nt] = (f32x4){0.f, 0.f, 0.f, 0.f};
#pragma unroll
        for (int r = 0; r < 4; r++) { m_r[j][r] = -INFINITY; l_r[j][r] = 0.f; }
    }

    stage(0, 0);
    __syncthreads();

    for (int c = 0; c < cmax; c++) {
        const int pb = c & 1;
        if (c + 1 < cmax) stage(c + 1, pb ^ 1);   // issue-early into other buffer

#pragma unroll
        for (int j = 0; j < 2; j++) {
            const int qt = w + 8 * j;
            if (qt < 13 && qt * 16 < ql) {         // skipped tiles -> epilogue inv=0
                const int q0 = qt * 16;
                const size_t qoff = (size_t)(b * T_ + q0 + mr) * E_ + h * 64 + q4 * 8;
                bf16x8 qe0 = *(const bf16x8*)&Qlo[qoff];
                bf16x8 qe1 = *(const bf16x8*)&Qlo[qoff + 32];

                f32x4 a[4];
#pragma unroll
                for (int kt = 0; kt < 4; kt++) a[kt] = (f32x4){0.f, 0.f, 0.f, 0.f};
                __builtin_amdgcn_s_setprio(1);
#pragma unroll
                for (int kt = 0; kt < 4; kt++) {
                    if (c * 64 + kt * 16 < 208) {   // skip fully-pad tiles (wave-uniform)
                        const int rbase = (kt * 16 + mr) * 72 + q4 * 8;
                        bf16x8 kh0 = *(const bf16x8*)&Kh_s[pb][rbase];
                        bf16x8 kh1 = *(const bf16x8*)&Kh_s[pb][rbase + 32];
                        bf16x8 ke0 = *(const bf16x8*)&Kl_s[pb][rbase];
                        bf16x8 ke1 = *(const bf16x8*)&Kl_s[pb][rbase + 32];
                        a[kt] = __builtin_amdgcn_mfma_f32_16x16x32_bf16(qh0[j], kh0, a[kt], 0, 0, 0);
                        a[kt] = __builtin_amdgcn_mfma_f32_16x16x32_bf16(qh1[j], kh1, a[kt], 0, 0, 0);
                        a[kt] = __builtin_amdgcn_mfma_f32_16x16x32_bf16(qh0[j], ke0, a[kt], 0, 0, 0);
                        a[kt] = __builtin_amdgcn_mfma_f32_16x16x32_bf16(qh1[j], ke1, a[kt], 0, 0, 0);
                        a[kt] = __builtin_amdgcn_mfma_f32_16x16x32_bf16(qe0, kh0, a[kt], 0, 0, 0);
                        a[kt] = __builtin_amdgcn_mfma_f32_16x16x32_bf16(qe1, kh1, a[kt], 0, 0, 0);
                    }
                }
                __builtin_amdgcn_s_setprio(0);

                // masks + chunk-local row max
                float mc[4] = {-INFINITY, -INFINITY, -INFINITY, -INFINITY};
#pragma unroll
                for (int kt = 0; kt < 4; kt++) {
                    int col = c * 64 + kt * 16 + mr;
#pragma unroll
                    for (int r = 0; r < 4; r++) {
                        int row = q0 + q4 * 4 + r;
                        float v = a[kt][r] * 0.125f;
                        if (col >= kl)  v = NEGV;
                        if (col == row) v = NEGV;
                        if (col >= T_)  v = -INFINITY;
                        a[kt][r] = v;
                        mc[r] = fmaxf(mc[r], v);
                    }
                }
#pragma unroll
                for (int r = 0; r < 4; r++)
#pragma unroll
                    for (int off = 1; off < 16; off <<= 1)
                        mc[r] = fmaxf(mc[r], __shfl_xor(mc[r], off));
                // online update: new max, rescale factor
                float mn[4], alpha[4], ps[4];
#pragma unroll
                for (int r = 0; r < 4; r++) {
                    mn[r] = fmaxf(m_r[j][r], mc[r]);
                    alpha[r] = __expf(m_r[j][r] - mn[r]);  // exp(-INF-finite)=0 at init
                    ps[r] = 0.f;
                }
#pragma unroll
                for (int kt = 0; kt < 4; kt++)
#pragma unroll
                    for (int r = 0; r < 4; r++) {
                        float p = __expf(a[kt][r] - mn[r]);  // pad col: exp(-INF)=0
                        a[kt][r] = p;
                        ps[r] += p;
                    }
#pragma unroll
                for (int r = 0; r < 4; r++)
#pragma unroll
                    for (int off = 1; off < 16; off <<= 1)
                        ps[r] += __shfl_xor(ps[r], off);
#pragma unroll
                for (int r = 0; r < 4; r++) {
                    l_r[j][r] = l_r[j][r] * alpha[r] + ps[r];
                    m_r[j][r] = mn[r];
                }
#pragma unroll
                for (int nt = 0; nt < 4; nt++)
#pragma unroll
                    for (int r = 0; r < 4; r++) O[j][nt][r] *= alpha[r];
                // P chunk -> per-wave LDS (unnormalized probs, bf16)
#pragma unroll
                for (int kt = 0; kt < 4; kt++)
#pragma unroll
                    for (int r = 0; r < 4; r++)
                        P_s[w][(q4 * 4 + r) * 72 + kt * 16 + mr] = f2bf(a[kt][r]);
                // PV over this chunk's 64 cols
                __builtin_amdgcn_s_setprio(1);
#pragma unroll
                for (int k2 = 0; k2 < 2; k2++) {
                    bf16x8 pf = *(const bf16x8*)&P_s[w][mr * 72 + k2 * 32 + q4 * 8];
#pragma unroll
                    for (int nt = 0; nt < 4; nt++) {
                        bf16x8 vf = *(const bf16x8*)&Vt_s[pb][(nt * 16 + mr) * 72 + k2 * 32 + q4 * 8];
                        O[j][nt] = __builtin_amdgcn_mfma_f32_16x16x32_bf16(pf, vf, O[j][nt], 0, 0, 0);
                    }
                }
                __builtin_amdgcn_s_setprio(0);
            }
        }
        __syncthreads();   // buf pb readers done; buf pb^1 staging complete
    }

    // epilogue: normalize by l (query mask folds in), + residual, in-place.
    // Skipped tiles (qt*16>=ql): O==0, rows>=ql -> inv=0 -> writes residual.
#pragma unroll
    for (int j = 0; j < 2; j++) {
        const int qt = w + 8 * j;
        if (qt < 13) {
#pragma unroll
            for (int r = 0; r < 4; r++) {
                int row = qt * 16 + q4 * 4 + r;
                if (row < T_) {
                    float inv = (row < ql) ? (1.f / l_r[j][r]) : 0.f;
#pragma unroll
                    for (int nt = 0; nt < 4; nt++) {
                        int d = nt * 16 + mr;
                        size_t gi = (size_t)(b * T_ + row) * E_ + h * 64 + d;
                        unsigned u = Apk[gi];
                        float res = bf2f((unsigned short)(u & 0xffff)) +
                                    bf2f((unsigned short)(u >> 16));
                        VX[gi] = f2bf(O[j][nt][r] * inv + res);
                    }
                }
            }
        }
    }
}

// ---------------------------------------------------------------------------
// Kernel 4: transpose+cast: in fp32 [K][N] -> out bf16 [N][K]  (for FFN)
// ---------------------------------------------------------------------------
__global__ __launch_bounds__(256) void k_tr(
    const float* __restrict__ in, unsigned short* __restrict__ out, int K, int N)
{
    const int k0 = blockIdx.x * 64, n0 = blockIdx.y * 64;
    const int tid = threadIdx.x;
    __shared__ unsigned short t[64][65];
#pragma unroll
    for (int i = 0; i < 16; i++) {
        int e = i * 256 + tid;
        int r = e >> 6, c = e & 63;
        t[r][c] = f2bf(in[(size_t)(k0 + r) * N + n0 + c]);
    }
    __syncthreads();
#pragma unroll
    for (int i = 0; i < 16; i++) {
        int e = i * 256 + tid;
        int r = e >> 6, c = e & 63;
        out[(size_t)(n0 + r) * K + k0 + c] = t[c][r];
    }
}

// ---------------------------------------------------------------------------
// Kernel 5: bf16 MFMA GEMM (m97 structure) — proven rounds 3/4/5
// ---------------------------------------------------------------------------
template<int K, int N, bool RELU, bool RES>
__global__ __launch_bounds__(256) void k_gemm_bt(
    const unsigned short* __restrict__ A,
    const unsigned short* __restrict__ Bt,
    unsigned short* __restrict__ C,
    const unsigned short* __restrict__ Res)
{
    __shared__ alignas(16) unsigned short As[128 * 32];
    __shared__ alignas(16) unsigned short Bs[128 * 32];

    const int tid  = threadIdx.x;
    const int w    = tid >> 6, lane = tid & 63;
    const int m0   = blockIdx.x * 128, n0 = blockIdx.y * 128;
    const int mr   = lane & 15, q = lane >> 4;

    f32x4 acc[4][4];
#pragma unroll
    for (int i = 0; i < 4; i++)
#pragma unroll
        for (int j = 0; j < 4; j++) acc[i][j] = (f32x4){0.f, 0.f, 0.f, 0.f};

    const int c0  = w * 64 + lane;
    const int c1  = 256 + w * 64 + lane;
    const int am0 = c0 >> 2, aq0 = (c0 & 3) ^ ((am0 >> 1) & 3);
    const int am1 = c1 >> 2, aq1 = (c1 & 3) ^ ((am1 >> 1) & 3);
    const unsigned short* gA0 = A  + (size_t)(m0 + am0) * K + aq0 * 8;
    const unsigned short* gA1 = A  + (size_t)(m0 + am1) * K + aq1 * 8;
    const unsigned short* gB0 = Bt + (size_t)(n0 + am0) * K + aq0 * 8;
    const unsigned short* gB1 = Bt + (size_t)(n0 + am1) * K + aq1 * 8;
    unsigned short* lA0 = As + (size_t)(w * 64) * 8;
    unsigned short* lA1 = As + (size_t)(256 + w * 64) * 8;
    unsigned short* lB0 = Bs + (size_t)(w * 64) * 8;
    unsigned short* lB1 = Bs + (size_t)(256 + w * 64) * 8;

    int caf[4], cbf[4];
#pragma unroll
    for (int t4 = 0; t4 < 4; t4++) {
        int ma = (w & 1) * 64 + t4 * 16 + mr;
        caf[t4] = ma * 4 + (q ^ ((ma >> 1) & 3));
        int nb = (w >> 1) * 64 + t4 * 16 + mr;
        cbf[t4] = nb * 4 + (q ^ ((nb >> 1) & 3));
    }

    for (int k0 = 0; k0 < K; k0 += 32) {
        load_lds16(gA0 + k0, lA0);
        load_lds16(gA1 + k0, lA1);
        load_lds16(gB0 + k0, lB0);
        load_lds16(gB1 + k0, lB1);
        __syncthreads();

        bf16x8 af[4], bg[4];
#pragma unroll
        for (int t4 = 0; t4 < 4; t4++) {
            af[t4] = *(const bf16x8*)&As[caf[t4] * 8];
            bg[t4] = *(const bf16x8*)&Bs[cbf[t4] * 8];
        }
#pragma unroll
        for (int i = 0; i < 4; i++)
#pragma unroll
            for (int j = 0; j < 4; j++)
                acc[i][j] = __builtin_amdgcn_mfma_f32_16x16x32_bf16(
                    af[i], bg[j], acc[i][j], 0, 0, 0);
        __syncthreads();
    }

#pragma unroll
    for (int i = 0; i < 4; i++) {
        int row = m0 + (w & 1) * 64 + i * 16 + q * 4;
#pragma unroll
        for (int j = 0; j < 4; j++) {
            int col = n0 + (w >> 1) * 64 + j * 16 + mr;
#pragma unroll
            for (int r = 0; r < 4; r++) {
                float v = acc[i][j][r];
                if (RELU) v = fmaxf(v, 0.f);
                if (RES)  v += bf2f(Res[(size_t)(row + r) * N + col]);
                C[(size_t)(row + r) * N + col] = f2bf(v);
            }
        }
    }
}

// ---------------------------------------------------------------------------
// Kernel 6: mean over T (bf16 in) -> (B,1,E) fp32 — v2: one block per b,
// each wave reads full 1 KB rows (16 B/lane) for t = w, w+4, ...; cross-wave
// reduce through LDS.  (Old version: 200 stride-1KB 2-byte loads/thread.)
// ---------------------------------------------------------------------------
__global__ __launch_bounds__(256) void k_mean(
    const unsigned short* __restrict__ out2, float* __restrict__ out)
{
    const int b = blockIdx.x;
    const int w = threadIdx.x >> 6, lane = threadIdx.x & 63;
    float s[8] = {0.f, 0.f, 0.f, 0.f, 0.f, 0.f, 0.f, 0.f};
    for (int t = w; t < T_; t += 4) {
        bf16x8 v = *(const bf16x8*)&out2[(size_t)(b * T_ + t) * E_ + lane * 8];
#pragma unroll
        for (int j = 0; j < 8; j++) s[j] += bf2f((unsigned short)v[j]);
    }
    __shared__ float red[4][512];
#pragma unroll
    for (int j = 0; j < 8; j++) red[w][lane * 8 + j] = s[j];
    __syncthreads();
#pragma unroll
    for (int e = threadIdx.x; e < 512; e += 256)
        out[(size_t)b * E_ + e] =
            (red[0][e] + red[1][e] + red[2][e] + red[3][e]) * (1.0f / 200.0f);
}

// ---------------------------------------------------------------------------
extern "C" void kernel_launch(void* const* d_in, const int* in_sizes, int n_in,
                              void* d_out, int out_size, void* d_ws, size_t ws_size,
                              hipStream_t stream)
{
    float* qmut = (float*)d_in[0];          // mutated in-place (restored by harness)
    float* kmut = (float*)d_in[1];
    const int*   qlen  = (const int*)d_in[2];
    const int*   klen  = (const int*)d_in[3];
    const float* pos_q = (const float*)d_in[4];
    const float* pos_k = (const float*)d_in[5];
    const float* W_Q   = (const float*)d_in[6];
    const float* W_K   = (const float*)d_in[7];
    const float* W_V   = (const float*)d_in[8];
    const float* fw1   = (const float*)d_in[9];
    const float* fw2   = (const float*)d_in[10];
    float* out = (float*)d_out;

    // ws layout — 250 MiB (proven).  R0..R3 = Qhi/Qlo/Khi/Klo (50 MiB each),
    // R4 = V.  wQ/wK transposed weights park in R4 head (dead before Vproj,
    // which runs last).  wV parks in the dead W_Q input buffer.
    char* base = (char*)d_ws;
    unsigned short* Qhi = (unsigned short*)base;
    unsigned short* Qlo = (unsigned short*)(base +  52428800);
    unsigned short* Khi = (unsigned short*)(base + 104857600);
    unsigned short* Klo = (unsigned short*)(base + 157286400);
    unsigned short* VX  = (unsigned short*)(base + 209715200);

    unsigned short* wQh = VX;               // 512 KB each
    unsigned short* wQl = VX + 262144;
    unsigned short* wKh = VX + 524288;
    unsigned short* wKl = VX + 786432;
    unsigned short* wVh = (unsigned short*)W_Q;          // dead after Qproj
    unsigned short* wVl = (unsigned short*)W_Q + 262144;

    unsigned short* Hbuf   = (unsigned short*)base;              // 100 MiB
    unsigned short* out2bf = (unsigned short*)(base + 104857600);// 50 MiB
    unsigned short* fw1t   = (unsigned short*)(base + 157286400);
    unsigned short* fw2t   = (unsigned short*)(base + 159383552);

    const unsigned int* Aq = (const unsigned int*)qmut;
    const unsigned int* Ak = (const unsigned int*)kmut;

    k_prep<<<dim3(M_ * E_ / 1024, 2), 256, 0, stream>>>(qmut, kmut, pos_q, pos_k);
    k_trw<<<dim3(8, 8), 256, 0, stream>>>(W_Q, wQh, wQl);
    k_trw<<<dim3(8, 8), 256, 0, stream>>>(W_K, wKh, wKl);
    k_projx<3, true><<<dim3(M_ / 128, 4), 256, 0, stream>>>(Aq, wQh, wQl, Qhi, Qlo);
    k_projx<3, true><<<dim3(M_ / 128, 4), 256, 0, stream>>>(Ak, wKh, wKl, Khi, Klo);
    k_trw<<<dim3(8, 8), 256, 0, stream>>>(W_V, wVh, wVl);
    k_projx<2, false><<<dim3(M_ / 128, 4), 256, 0, stream>>>(Ak, wVh, nullptr, VX, nullptr);

    k_attn_flash<<<B_ * H_, 512, 0, stream>>>(
        Qhi, Qlo, Khi, Klo, qlen, klen, Aq, VX);

    k_tr<<<dim3(E_ / 64, F_ / 64), 256, 0, stream>>>(fw1, fw1t, E_, F_);
    k_tr<<<dim3(F_ / 64, E_ / 64), 256, 0, stream>>>(fw2, fw2t, F_, E_);

    for (int c = 0; c < 2; c++) {
        const unsigned short* Xc = VX + (size_t)c * MH_ * E_;
        unsigned short* Oc = out2bf + (size_t)c * MH_ * E_;
        k_gemm_bt<E_, F_, true, false><<<dim3(MH_ / 128, F_ / 128), 256, 0, stream>>>(
            Xc, fw1t, Hbuf, nullptr);
        k_gemm_bt<F_, E_, false, true><<<dim3(MH_ / 128, E_ / 128), 256, 0, stream>>>(
            Hbuf, fw2t, Oc, Xc);
    }
    k_mean<<<B_, 256, 0, stream>>>(out2bf, out);
}

// Round 2
// 923.573 us; speedup vs baseline: 1.2914x; 1.1018x over previous
//
#include <hip/hip_runtime.h>

// Problem constants (B,T,E,H fixed by the reference)
#define B_   256
#define T_   200
#define E_   512
#define H_   8
#define Dh_  64
#define F_   2048            // 4*E
#define M_   (B_ * T_)       // 51200 rows
#define SCALE 22.62741699796952f   // sqrt(512) in fp32
#define NEGV  -4294967296.0f       // fp32(-(2^32)+1)

typedef __attribute__((ext_vector_type(8))) short bf16x8;
typedef __attribute__((ext_vector_type(4))) float f32x4;

__device__ __forceinline__ float bf2f(unsigned short u) {
    union { unsigned u32; float f; } v; v.u32 = ((unsigned)u) << 16; return v.f;
}
__device__ __forceinline__ unsigned short f2bf(float f) {
    union { float f32; unsigned u; } v; v.f32 = f;
    unsigned r = v.u + 0x7FFFu + ((v.u >> 16) & 1u);   // RNE
    return (unsigned short)(r >> 16);
}
__device__ __forceinline__ unsigned pack_hilo(float f) {
    unsigned short hi = f2bf(f);
    unsigned short lo = f2bf(f - bf2f(hi));
    return (unsigned)hi | ((unsigned)lo << 16);
}
__device__ __forceinline__ void load_lds16(const void* g, void* l) {
    __builtin_amdgcn_global_load_lds(
        (const __attribute__((address_space(1))) unsigned int*)g,
        (__attribute__((address_space(3))) unsigned int*)l, 16, 0, 0);
}

// ---------------------------------------------------------------------------
// Kernel 0: pos-encoding add + hi/lo bf16 split, IN-PLACE over queries/keys.
// ---------------------------------------------------------------------------
__global__ __launch_bounds__(256) void k_prep(
    float* __restrict__ q, float* __restrict__ k,
    const float* __restrict__ pos_q, const float* __restrict__ pos_k)
{
    const int z = blockIdx.y;
    float* X = z ? k : q;
    const float* Ps = z ? pos_k : pos_q;
    size_t idx = ((size_t)blockIdx.x * 256 + threadIdx.x) * 4;
    int row = (int)(idx >> 9);
    int col = (int)(idx & 511);
    int t = row % T_;
    float4 v = *(const float4*)&X[idx];
    float4 p = *(const float4*)&Ps[(size_t)t * E_ + col];
    uint4 o;
    o.x = pack_hilo(v.x + p.x * SCALE);
    o.y = pack_hilo(v.y + p.y * SCALE);
    o.z = pack_hilo(v.z + p.z * SCALE);
    o.w = pack_hilo(v.w + p.w * SCALE);
    *(uint4*)&X[idx] = o;
}

// ---------------------------------------------------------------------------
// Kernel 1: weight transpose + hi/lo split: W fp32 [K][N] -> Wh,Wl bf16 [N][K]
// ---------------------------------------------------------------------------
__global__ __launch_bounds__(256) void k_trw(
    const float* __restrict__ in, unsigned short* __restrict__ oh,
    unsigned short* __restrict__ ol)
{
    const int k0 = blockIdx.x * 64, n0 = blockIdx.y * 64;
    const int tid = threadIdx.x;
    __shared__ unsigned short th[64][65], tl[64][65];
#pragma unroll
    for (int i = 0; i < 16; i++) {
        int e = i * 256 + tid;
        int r = e >> 6, c = e & 63;
        float f = in[(size_t)(k0 + r) * 512 + n0 + c];
        unsigned short h = f2bf(f);
        th[r][c] = h;
        tl[r][c] = f2bf(f - bf2f(h));
    }
    __syncthreads();
#pragma unroll
    for (int i = 0; i < 16; i++) {
        int e = i * 256 + tid;
        int r = e >> 6, c = e & 63;
        oh[(size_t)(n0 + r) * 512 + k0 + c] = th[c][r];
        ol[(size_t)(n0 + r) * 512 + k0 + c] = tl[c][r];
    }
}

// ---------------------------------------------------------------------------
// Kernel 2: split-precision projection GEMM via MFMA — v2 (this round).
//   A path is now PURE DMA: packed u32 elements staged to LDS with
//   global_load_lds (16B-chunk XOR swizzle via pre-swizzled SOURCE address,
//   linear LDS dest — m97/m173 pattern).  hi/lo planes are separated at
//   fragment-read time with 2 ds_read_b128 + 8 bit-ops (v_perm-foldable).
//   Kills the ~8-VALU/element unpack-staging loop that dominated VALUBusy.
//   Template: K (512 proj / 2048 ffn-mini), NPROD (3 = AhBh+AhBl+AlBh,
//   2 = AhBh+AlBh), SPLIT (write hi+lo outputs), FOUT (fp32 output).
// ---------------------------------------------------------------------------
template<int K, int NPROD, bool SPLIT, bool FOUT>
__global__ __launch_bounds__(256) void k_projx(
    const unsigned int* __restrict__ Apk,
    const unsigned short* __restrict__ Bh,
    const unsigned short* __restrict__ Bl,
    unsigned short* __restrict__ Chi,
    unsigned short* __restrict__ Clo)
{
    const int N = 512;
    __shared__ alignas(16) unsigned int   Asp[128 * 32];   // packed dwords, 16 KB
    __shared__ alignas(16) unsigned short BsH[128 * 32];   // 8 KB
    __shared__ alignas(16) unsigned short BsL[(NPROD >= 3) ? 128 * 32 : 8];

    const int tid = threadIdx.x;
    const int w = tid >> 6, lane = tid & 63;
    const int m0 = blockIdx.x * 128, n0 = blockIdx.y * 128;
    const int mr = lane & 15, q4 = lane >> 4;

    f32x4 acc[4][4];
#pragma unroll
    for (int i = 0; i < 4; i++)
#pragma unroll
        for (int j = 0; j < 4; j++) acc[i][j] = (f32x4){0.f, 0.f, 0.f, 0.f};

    // A staging: 1024 16B chunks (128 rows x 8 chunks/row).  LDS linear in
    // chunk index c; global source chunk = cc ^ (row&7)  (involution).
    const unsigned int* gA[4];
    unsigned int* lA[4];
#pragma unroll
    for (int it = 0; it < 4; it++) {
        int c = it * 256 + tid;
        int row = c >> 3, cc = c & 7;
        gA[it] = Apk + (size_t)(m0 + row) * K + ((cc ^ (row & 7)) * 4);
        lA[it] = Asp + (size_t)(it * 256 + w * 64) * 4;
    }
    // B staging (proven m97 pattern)
    const int c0  = w * 64 + lane;
    const int c1  = 256 + c0;
    const int bm0 = c0 >> 2, bq0 = (c0 & 3) ^ ((bm0 >> 1) & 3);
    const int bm1 = c1 >> 2, bq1 = (c1 & 3) ^ ((bm1 >> 1) & 3);
    const unsigned short* gB0h = Bh + (size_t)(n0 + bm0) * K + bq0 * 8;
    const unsigned short* gB1h = Bh + (size_t)(n0 + bm1) * K + bq1 * 8;
    const unsigned short* gB0l = (NPROD >= 3) ? Bl + (size_t)(n0 + bm0) * K + bq0 * 8 : nullptr;
    const unsigned short* gB1l = (NPROD >= 3) ? Bl + (size_t)(n0 + bm1) * K + bq1 * 8 : nullptr;
    unsigned short* lB0h = BsH + (size_t)(w * 64) * 8;
    unsigned short* lB1h = BsH + (size_t)(256 + w * 64) * 8;
    unsigned short* lB0l = BsL + (size_t)(w * 64) * 8;
    unsigned short* lB1l = BsL + (size_t)(256 + w * 64) * 8;

    int cbf[4];
#pragma unroll
    for (int t4 = 0; t4 < 4; t4++) {
        int nb = (w >> 1) * 64 + t4 * 16 + mr;
        cbf[t4] = nb * 4 + (q4 ^ ((nb >> 1) & 3));
    }
    const int ra_base = (w & 1) * 64;

    for (int k0 = 0; k0 < K; k0 += 32) {
#pragma unroll
        for (int it = 0; it < 4; it++) load_lds16(gA[it] + k0, lA[it]);
        load_lds16(gB0h + k0, lB0h);
        load_lds16(gB1h + k0, lB1h);
        if (NPROD >= 3) {
            load_lds16(gB0l + k0, lB0l);
            load_lds16(gB1l + k0, lB1l);
        }
        __syncthreads();

        bf16x8 afh[4], afl[4], bgh[4], bgl[4];
#pragma unroll
        for (int t4 = 0; t4 < 4; t4++) {
            const int ra = ra_base + t4 * 16 + mr;
            const int r7 = ra & 7;
            uint4 u0 = *(const uint4*)&Asp[(size_t)(ra * 8 + ((q4 * 2) ^ r7)) * 4];
            uint4 u1 = *(const uint4*)&Asp[(size_t)(ra * 8 + ((q4 * 2 + 1) ^ r7)) * 4];
            union { unsigned u[4]; bf16x8 v; } Hh, Ll;
            Hh.u[0] = (u0.x & 0xffffu) | (u0.y << 16);
            Hh.u[1] = (u0.z & 0xffffu) | (u0.w << 16);
            Hh.u[2] = (u1.x & 0xffffu) | (u1.y << 16);
            Hh.u[3] = (u1.z & 0xffffu) | (u1.w << 16);
            afh[t4] = Hh.v;
            Ll.u[0] = (u0.x >> 16) | (u0.y & 0xffff0000u);
            Ll.u[1] = (u0.z >> 16) | (u0.w & 0xffff0000u);
            Ll.u[2] = (u1.x >> 16) | (u1.y & 0xffff0000u);
            Ll.u[3] = (u1.z >> 16) | (u1.w & 0xffff0000u);
            afl[t4] = Ll.v;
            bgh[t4] = *(const bf16x8*)&BsH[cbf[t4] * 8];
            if (NPROD >= 3) bgl[t4] = *(const bf16x8*)&BsL[cbf[t4] * 8];
        }
#pragma unroll
        for (int i = 0; i < 4; i++)
#pragma unroll
            for (int j = 0; j < 4; j++) {
                acc[i][j] = __builtin_amdgcn_mfma_f32_16x16x32_bf16(
                    afh[i], bgh[j], acc[i][j], 0, 0, 0);
                if (NPROD >= 3)
                    acc[i][j] = __builtin_amdgcn_mfma_f32_16x16x32_bf16(
                        afh[i], bgl[j], acc[i][j], 0, 0, 0);
                acc[i][j] = __builtin_amdgcn_mfma_f32_16x16x32_bf16(
                    afl[i], bgh[j], acc[i][j], 0, 0, 0);
            }
        __syncthreads();
    }

#pragma unroll
    for (int i = 0; i < 4; i++) {
        int row = m0 + (w & 1) * 64 + i * 16 + (lane >> 4) * 4;
#pragma unroll
        for (int j = 0; j < 4; j++) {
            int col = n0 + (w >> 1) * 64 + j * 16 + mr;
#pragma unroll
            for (int r = 0; r < 4; r++) {
                float v = acc[i][j][r];
                if (FOUT) {
                    ((float*)Chi)[(size_t)(row + r) * N + col] = v;
                } else {
                    unsigned short hi = f2bf(v);
                    Chi[(size_t)(row + r) * N + col] = hi;
                    if (SPLIT)
                        Clo[(size_t)(row + r) * N + col] = f2bf(v - bf2f(hi));
                }
            }
        }
    }
}

// ---------------------------------------------------------------------------
// Kernel 3: FLASH attention per (b,h) — proven round 1 (unchanged).
// ---------------------------------------------------------------------------
__global__ __launch_bounds__(512, 4) void k_attn_flash(
    const unsigned short* __restrict__ Qhi, const unsigned short* __restrict__ Qlo,
    const unsigned short* __restrict__ Khi, const unsigned short* __restrict__ Klo,
    const int* __restrict__ qlen, const int* __restrict__ klen,
    const unsigned int* __restrict__ Apk,   // packed q_in hi/lo (residual)
    unsigned short* VX)   // V (read) and out1 (write) — same buffer
{
    const int bh = blockIdx.x;
    const int b = bh >> 3, h = bh & 7;
    const int tid = threadIdx.x;
    const int w = tid >> 6, l = tid & 63;
    const int mr = l & 15, q4 = l >> 4;

    __shared__ alignas(16) unsigned short Kh_s[2][64 * 72];
    __shared__ alignas(16) unsigned short Kl_s[2][64 * 72];
    __shared__ alignas(16) unsigned short Vt_s[2][64 * 72];
    __shared__ alignas(16) unsigned short P_s[8][16 * 72];

    const int kl = klen[b], ql = qlen[b];
    const int cmax = (kl > 1) ? ((kl + 63) >> 6) : 4;

    auto stage = [&](int cs, int sb) {
#pragma unroll
        for (int ii = 0; ii < 2; ii++) {
            const int idx = ii * 512 + tid;
            const int jn = idx >> 4, dq = idx & 15;
            const int n = cs * 64 + jn;
            if (n < T_) {
                const size_t g = (size_t)(b * T_ + n) * E_ + h * 64 + dq * 4;
                *(uint2*)&Kh_s[sb][jn * 72 + dq * 4] = *(const uint2*)&Khi[g];
                *(uint2*)&Kl_s[sb][jn * 72 + dq * 4] = *(const uint2*)&Klo[g];
                ushort4 v = *(const ushort4*)&VX[g];
                Vt_s[sb][(dq * 4 + 0) * 72 + jn] = v.x;
                Vt_s[sb][(dq * 4 + 1) * 72 + jn] = v.y;
                Vt_s[sb][(dq * 4 + 2) * 72 + jn] = v.z;
                Vt_s[sb][(dq * 4 + 3) * 72 + jn] = v.w;
            } else {
                Vt_s[sb][(dq * 4 + 0) * 72 + jn] = 0;
                Vt_s[sb][(dq * 4 + 1) * 72 + jn] = 0;
                Vt_s[sb][(dq * 4 + 2) * 72 + jn] = 0;
                Vt_s[sb][(dq * 4 + 3) * 72 + jn] = 0;
            }
        }
    };

    bf16x8 qh0[2], qh1[2];
#pragma unroll
    for (int j = 0; j < 2; j++) {
        const int qt = w + 8 * j;
        if (qt < 13 && qt * 16 < ql) {
            const size_t qoff = (size_t)(b * T_ + qt * 16 + mr) * E_ + h * 64 + q4 * 8;
            qh0[j] = *(const bf16x8*)&Qhi[qoff];
            qh1[j] = *(const bf16x8*)&Qhi[qoff + 32];
        }
    }

    f32x4 O[2][4];
    float m_r[2][4], l_r[2][4];
#pragma unroll
    for (int j = 0; j < 2; j++) {
#pragma unroll
        for (int nt = 0; nt < 4; nt++) O[j][nt] = (f32x4){0.f, 0.f, 0.f, 0.f};
#pragma unroll
        for (int r = 0; r < 4; r++) { m_r[j][r] = -INFINITY; l_r[j][r] = 0.f; }
    }

    stage(0, 0);
    __syncthreads();

    for (int c = 0; c < cmax; c++) {
        const int pb = c & 1;
        if (c + 1 < cmax) stage(c + 1, pb ^ 1);

#pragma unroll
        for (int j = 0; j < 2; j++) {
            const int qt = w + 8 * j;
            if (qt < 13 && qt * 16 < ql) {
                const int q0 = qt * 16;
                const size_t qoff = (size_t)(b * T_ + q0 + mr) * E_ + h * 64 + q4 * 8;
                bf16x8 qe0 = *(const bf16x8*)&Qlo[qoff];
                bf16x8 qe1 = *(const bf16x8*)&Qlo[qoff + 32];

                f32x4 a[4];
#pragma unroll
                for (int kt = 0; kt < 4; kt++) a[kt] = (f32x4){0.f, 0.f, 0.f, 0.f};
                __builtin_amdgcn_s_setprio(1);
#pragma unroll
                for (int kt = 0; kt < 4; kt++) {
                    if (c * 64 + kt * 16 < 208) {
                        const int rbase = (kt * 16 + mr) * 72 + q4 * 8;
                        bf16x8 kh0 = *(const bf16x8*)&Kh_s[pb][rbase];
                        bf16x8 kh1 = *(const bf16x8*)&Kh_s[pb][rbase + 32];
                        bf16x8 ke0 = *(const bf16x8*)&Kl_s[pb][rbase];
                        bf16x8 ke1 = *(const bf16x8*)&Kl_s[pb][rbase + 32];
                        a[kt] = __builtin_amdgcn_mfma_f32_16x16x32_bf16(qh0[j], kh0, a[kt], 0, 0, 0);
                        a[kt] = __builtin_amdgcn_mfma_f32_16x16x32_bf16(qh1[j], kh1, a[kt], 0, 0, 0);
                        a[kt] = __builtin_amdgcn_mfma_f32_16x16x32_bf16(qh0[j], ke0, a[kt], 0, 0, 0);
                        a[kt] = __builtin_amdgcn_mfma_f32_16x16x32_bf16(qh1[j], ke1, a[kt], 0, 0, 0);
                        a[kt] = __builtin_amdgcn_mfma_f32_16x16x32_bf16(qe0, kh0, a[kt], 0, 0, 0);
                        a[kt] = __builtin_amdgcn_mfma_f32_16x16x32_bf16(qe1, kh1, a[kt], 0, 0, 0);
                    }
                }
                __builtin_amdgcn_s_setprio(0);

                float mc[4] = {-INFINITY, -INFINITY, -INFINITY, -INFINITY};
#pragma unroll
                for (int kt = 0; kt < 4; kt++) {
                    int col = c * 64 + kt * 16 + mr;
#pragma unroll
                    for (int r = 0; r < 4; r++) {
                        int row = q0 + q4 * 4 + r;
                        float v = a[kt][r] * 0.125f;
                        if (col >= kl)  v = NEGV;
                        if (col == row) v = NEGV;
                        if (col >= T_)  v = -INFINITY;
                        a[kt][r] = v;
                        mc[r] = fmaxf(mc[r], v);
                    }
                }
#pragma unroll
                for (int r = 0; r < 4; r++)
#pragma unroll
                    for (int off = 1; off < 16; off <<= 1)
                        mc[r] = fmaxf(mc[r], __shfl_xor(mc[r], off));
                float mn[4], alpha[4], ps[4];
#pragma unroll
                for (int r = 0; r < 4; r++) {
                    mn[r] = fmaxf(m_r[j][r], mc[r]);
                    alpha[r] = __expf(m_r[j][r] - mn[r]);
                    ps[r] = 0.f;
                }
#pragma unroll
                for (int kt = 0; kt < 4; kt++)
#pragma unroll
                    for (int r = 0; r < 4; r++) {
                        float p = __expf(a[kt][r] - mn[r]);
                        a[kt][r] = p;
                        ps[r] += p;
                    }
#pragma unroll
                for (int r = 0; r < 4; r++)
#pragma unroll
                    for (int off = 1; off < 16; off <<= 1)
                        ps[r] += __shfl_xor(ps[r], off);
#pragma unroll
                for (int r = 0; r < 4; r++) {
                    l_r[j][r] = l_r[j][r] * alpha[r] + ps[r];
                    m_r[j][r] = mn[r];
                }
#pragma unroll
                for (int nt = 0; nt < 4; nt++)
#pragma unroll
                    for (int r = 0; r < 4; r++) O[j][nt][r] *= alpha[r];
#pragma unroll
                for (int kt = 0; kt < 4; kt++)
#pragma unroll
                    for (int r = 0; r < 4; r++)
                        P_s[w][(q4 * 4 + r) * 72 + kt * 16 + mr] = f2bf(a[kt][r]);
                __builtin_amdgcn_s_setprio(1);
#pragma unroll
                for (int k2 = 0; k2 < 2; k2++) {
                    bf16x8 pf = *(const bf16x8*)&P_s[w][mr * 72 + k2 * 32 + q4 * 8];
#pragma unroll
                    for (int nt = 0; nt < 4; nt++) {
                        bf16x8 vf = *(const bf16x8*)&Vt_s[pb][(nt * 16 + mr) * 72 + k2 * 32 + q4 * 8];
                        O[j][nt] = __builtin_amdgcn_mfma_f32_16x16x32_bf16(pf, vf, O[j][nt], 0, 0, 0);
                    }
                }
                __builtin_amdgcn_s_setprio(0);
            }
        }
        __syncthreads();
    }

#pragma unroll
    for (int j = 0; j < 2; j++) {
        const int qt = w + 8 * j;
        if (qt < 13) {
#pragma unroll
            for (int r = 0; r < 4; r++) {
                int row = qt * 16 + q4 * 4 + r;
                if (row < T_) {
                    float inv = (row < ql) ? (1.f / l_r[j][r]) : 0.f;
#pragma unroll
                    for (int nt = 0; nt < 4; nt++) {
                        int d = nt * 16 + mr;
                        size_t gi = (size_t)(b * T_ + row) * E_ + h * 64 + d;
                        unsigned u = Apk[gi];
                        float res = bf2f((unsigned short)(u & 0xffff)) +
                                    bf2f((unsigned short)(u >> 16));
                        VX[gi] = f2bf(O[j][nt][r] * inv + res);
                    }
                }
            }
        }
    }
}

// ---------------------------------------------------------------------------
// Kernel 4: transpose+cast: in fp32 [K][N] -> out bf16 [N][K]  (for FFN)
// ---------------------------------------------------------------------------
__global__ __launch_bounds__(256) void k_tr(
    const float* __restrict__ in, unsigned short* __restrict__ out, int K, int N)
{
    const int k0 = blockIdx.x * 64, n0 = blockIdx.y * 64;
    const int tid = threadIdx.x;
    __shared__ unsigned short t[64][65];
#pragma unroll
    for (int i = 0; i < 16; i++) {
        int e = i * 256 + tid;
        int r = e >> 6, c = e & 63;
        t[r][c] = f2bf(in[(size_t)(k0 + r) * N + n0 + c]);
    }
    __syncthreads();
#pragma unroll
    for (int i = 0; i < 16; i++) {
        int e = i * 256 + tid;
        int r = e >> 6, c = e & 63;
        out[(size_t)(n0 + r) * K + k0 + c] = t[c][r];
    }
}

// ---------------------------------------------------------------------------
// Kernel 5: FFN GEMM1 with fused relu + per-batch column-sum epilogue.
// mean_t(relu(H)@fw2) == (mean_t relu(H)) @ fw2, so H is NEVER materialized:
// each block reduces relu(acc) over its 128 rows grouped by batch (a 128-row
// tile crosses at most one batch boundary), LDS-reduces to [2][128] partial
// col-sums, then <=256 global fp32 atomicAdds into Hsum[256][2048].
// ---------------------------------------------------------------------------
__global__ __launch_bounds__(256) void k_gemm_relusum(
    const unsigned short* __restrict__ A,     // VX (out1) 51200x512 bf16
    const unsigned short* __restrict__ Bt,    // fw1t 2048x512 bf16
    float* __restrict__ Hsum)                 // 256x2048 fp32 (pre-zeroed)
{
    const int K = E_, N = F_;
    __shared__ alignas(16) unsigned short As[128 * 32];
    __shared__ alignas(16) unsigned short Bs[128 * 32];
    __shared__ float colsum[2][128];

    const int tid  = threadIdx.x;
    const int w    = tid >> 6, lane = tid & 63;
    const int m0   = blockIdx.x * 128, n0 = blockIdx.y * 128;
    const int mr   = lane & 15, q = lane >> 4;

    f32x4 acc[4][4];
#pragma unroll
    for (int i = 0; i < 4; i++)
#pragma unroll
        for (int j = 0; j < 4; j++) acc[i][j] = (f32x4){0.f, 0.f, 0.f, 0.f};

    const int c0  = w * 64 + lane;
    const int c1  = 256 + w * 64 + lane;
    const int am0 = c0 >> 2, aq0 = (c0 & 3) ^ ((am0 >> 1) & 3);
    const int am1 = c1 >> 2, aq1 = (c1 & 3) ^ ((am1 >> 1) & 3);
    const unsigned short* gA0 = A  + (size_t)(m0 + am0) * K + aq0 * 8;
    const unsigned short* gA1 = A  + (size_t)(m0 + am1) * K + aq1 * 8;
    const unsigned short* gB0 = Bt + (size_t)(n0 + am0) * K + aq0 * 8;
    const unsigned short* gB1 = Bt + (size_t)(n0 + am1) * K + aq1 * 8;
    unsigned short* lA0 = As + (size_t)(w * 64) * 8;
    unsigned short* lA1 = As + (size_t)(256 + w * 64) * 8;
    unsigned short* lB0 = Bs + (size_t)(w * 64) * 8;
    unsigned short* lB1 = Bs + (size_t)(256 + w * 64) * 8;

    int caf[4], cbf[4];
#pragma unroll
    for (int t4 = 0; t4 < 4; t4++) {
        int ma = (w & 1) * 64 + t4 * 16 + mr;
        caf[t4] = ma * 4 + (q ^ ((ma >> 1) & 3));
        int nb = (w >> 1) * 64 + t4 * 16 + mr;
        cbf[t4] = nb * 4 + (q ^ ((nb >> 1) & 3));
    }

    for (int k0 = 0; k0 < K; k0 += 32) {
        load_lds16(gA0 + k0, lA0);
        load_lds16(gA1 + k0, lA1);
        load_lds16(gB0 + k0, lB0);
        load_lds16(gB1 + k0, lB1);
        __syncthreads();

        bf16x8 af[4], bg[4];
#pragma unroll
        for (int t4 = 0; t4 < 4; t4++) {
            af[t4] = *(const bf16x8*)&As[caf[t4] * 8];
            bg[t4] = *(const bf16x8*)&Bs[cbf[t4] * 8];
        }
#pragma unroll
        for (int i = 0; i < 4; i++)
#pragma unroll
            for (int j = 0; j < 4; j++)
                acc[i][j] = __builtin_amdgcn_mfma_f32_16x16x32_bf16(
                    af[i], bg[j], acc[i][j], 0, 0, 0);
        __syncthreads();
    }

    // relu + per-batch row-sum epilogue
    ((float*)colsum)[tid] = 0.f;
    __syncthreads();
    const int b0 = m0 / 200;
    const int bsplit = (b0 + 1) * 200;   // first row of batch b0+1
#pragma unroll
    for (int j = 0; j < 4; j++) {
        const int colr = (w >> 1) * 64 + j * 16 + mr;
        float s0 = 0.f, s1 = 0.f;
#pragma unroll
        for (int i = 0; i < 4; i++) {
            const int rowb = m0 + (w & 1) * 64 + i * 16 + q * 4;
#pragma unroll
            for (int r = 0; r < 4; r++) {
                float v = fmaxf(acc[i][j][r], 0.f);
                if (rowb + r >= bsplit) s1 += v; else s0 += v;
            }
        }
        atomicAdd(&colsum[0][colr], s0);
        atomicAdd(&colsum[1][colr], s1);
    }
    __syncthreads();
    if (tid < 128) {
        atomicAdd(&Hsum[(size_t)b0 * N + n0 + tid], colsum[0][tid]);
        if (bsplit < m0 + 128)
            atomicAdd(&Hsum[(size_t)(b0 + 1) * N + n0 + tid], colsum[1][tid]);
    }
}

// ---------------------------------------------------------------------------
// Kernel 6: zero Hsum (2 MiB)
// ---------------------------------------------------------------------------
__global__ __launch_bounds__(256) void k_zero(float* __restrict__ p)
{
    ((float4*)p)[(size_t)blockIdx.x * 256 + threadIdx.x] = (float4){0.f, 0.f, 0.f, 0.f};
}

// ---------------------------------------------------------------------------
// Kernel 7: Hsum -> packed hi/lo bf16 of the T-mean (x 1/200)
// ---------------------------------------------------------------------------
__global__ __launch_bounds__(256) void k_hm(
    const float* __restrict__ Hsum, unsigned int* __restrict__ Hmpk)
{
    size_t idx = ((size_t)blockIdx.x * 256 + threadIdx.x) * 4;
    float4 v = *(const float4*)&Hsum[idx];
    uint4 o;
    o.x = pack_hilo(v.x * (1.0f / 200.0f));
    o.y = pack_hilo(v.y * (1.0f / 200.0f));
    o.z = pack_hilo(v.z * (1.0f / 200.0f));
    o.w = pack_hilo(v.w * (1.0f / 200.0f));
    *(uint4*)&Hmpk[idx] = o;
}

// ---------------------------------------------------------------------------
// Kernel 8: final: out[b][e] = mean_t(out1[b,:,e]) + ffm[b][e]
// ---------------------------------------------------------------------------
__global__ __launch_bounds__(256) void k_final(
    const unsigned short* __restrict__ X, const float* __restrict__ ffm,
    float* __restrict__ out)
{
    const int b = blockIdx.x;
    const int w = threadIdx.x >> 6, lane = threadIdx.x & 63;
    float s[8] = {0.f, 0.f, 0.f, 0.f, 0.f, 0.f, 0.f, 0.f};
    for (int t = w; t < T_; t += 4) {
        bf16x8 v = *(const bf16x8*)&X[(size_t)(b * T_ + t) * E_ + lane * 8];
#pragma unroll
        for (int j = 0; j < 8; j++) s[j] += bf2f((unsigned short)v[j]);
    }
    __shared__ float red[4][512];
#pragma unroll
    for (int j = 0; j < 8; j++) red[w][lane * 8 + j] = s[j];
    __syncthreads();
    for (int e = threadIdx.x; e < 512; e += 256)
        out[(size_t)b * E_ + e] =
            (red[0][e] + red[1][e] + red[2][e] + red[3][e]) * (1.0f / 200.0f) +
            ffm[(size_t)b * E_ + e];
}

// ---------------------------------------------------------------------------
extern "C" void kernel_launch(void* const* d_in, const int* in_sizes, int n_in,
                              void* d_out, int out_size, void* d_ws, size_t ws_size,
                              hipStream_t stream)
{
    float* qmut = (float*)d_in[0];          // mutated in-place (restored by harness)
    float* kmut = (float*)d_in[1];
    const int*   qlen  = (const int*)d_in[2];
    const int*   klen  = (const int*)d_in[3];
    const float* pos_q = (const float*)d_in[4];
    const float* pos_k = (const float*)d_in[5];
    const float* W_Q   = (const float*)d_in[6];
    const float* W_K   = (const float*)d_in[7];
    const float* W_V   = (const float*)d_in[8];
    const float* fw1   = (const float*)d_in[9];
    const float* fw2   = (const float*)d_in[10];
    float* out = (float*)d_out;

    // ws layout — 250 MiB.  R0..R3 = Qhi/Qlo/Khi/Klo (50 MiB each), R4 = VX.
    // wQ/wK transposed weights park in R4 head (dead before Vproj).  wV parks
    // in the dead W_Q input buffer.  Post-attention, the dead Klo region
    // hosts fw1t/fw2t/Hsum/Hmpk/ffm.
    char* base = (char*)d_ws;
    unsigned short* Qhi = (unsigned short*)base;
    unsigned short* Qlo = (unsigned short*)(base +  52428800);
    unsigned short* Khi = (unsigned short*)(base + 104857600);
    unsigned short* Klo = (unsigned short*)(base + 157286400);
    unsigned short* VX  = (unsigned short*)(base + 209715200);

    unsigned short* wQh = VX;               // 512 KB each
    unsigned short* wQl = VX + 262144;
    unsigned short* wKh = VX + 524288;
    unsigned short* wKl = VX + 786432;
    unsigned short* wVh = (unsigned short*)W_Q;          // dead after Qproj
    unsigned short* wVl = (unsigned short*)W_Q + 262144;

    unsigned short* fw1t = (unsigned short*)(base + 157286400);   // 2 MiB
    unsigned short* fw2t = (unsigned short*)(base + 159383552);   // 2 MiB
    float*        Hsum = (float*)(base + 161480704);              // 2 MiB
    unsigned int* Hmpk = (unsigned int*)(base + 163577856);       // 2 MiB
    float*        ffm  = (float*)(base + 165675008);              // 512 KiB

    const unsigned int* Aq = (const unsigned int*)qmut;
    const unsigned int* Ak = (const unsigned int*)kmut;

    k_prep<<<dim3(M_ * E_ / 1024, 2), 256, 0, stream>>>(qmut, kmut, pos_q, pos_k);
    k_trw<<<dim3(8, 8), 256, 0, stream>>>(W_Q, wQh, wQl);
    k_trw<<<dim3(8, 8), 256, 0, stream>>>(W_K, wKh, wKl);
    k_projx<512, 3, true, false><<<dim3(M_ / 128, 4), 256, 0, stream>>>(
        Aq, wQh, wQl, Qhi, Qlo);
    k_projx<512, 3, true, false><<<dim3(M_ / 128, 4), 256, 0, stream>>>(
        Ak, wKh, wKl, Khi, Klo);
    k_trw<<<dim3(8, 8), 256, 0, stream>>>(W_V, wVh, wVl);
    k_projx<512, 2, false, false><<<dim3(M_ / 128, 4), 256, 0, stream>>>(
        Ak, wVh, nullptr, VX, nullptr);

    k_attn_flash<<<B_ * H_, 512, 0, stream>>>(
        Qhi, Qlo, Khi, Klo, qlen, klen, Aq, VX);

    k_tr<<<dim3(E_ / 64, F_ / 64), 256, 0, stream>>>(fw1, fw1t, E_, F_);
    k_tr<<<dim3(F_ / 64, E_ / 64), 256, 0, stream>>>(fw2, fw2t, F_, E_);
    k_zero<<<512, 256, 0, stream>>>(Hsum);

    k_gemm_relusum<<<dim3(M_ / 128, F_ / 128), 256, 0, stream>>>(VX, fw1t, Hsum);
    k_hm<<<512, 256, 0, stream>>>(Hsum, Hmpk);
    k_projx<2048, 2, false, true><<<dim3(2, 4), 256, 0, stream>>>(
        Hmpk, fw2t, nullptr, (unsigned short*)ffm, nullptr);
    k_final<<<B_, 256, 0, stream>>>(VX, ffm, out);
}